// Round 4
// baseline (482.176 us; speedup 1.0000x reference)
//
#include <hip/hip_runtime.h>
#include <hip/hip_bf16.h>
#include <stdint.h>

#define SEQLEN 4096
#define DMODEL 1024

typedef uint16_t u16;
typedef uint32_t u32;

typedef __bf16 bf16x8 __attribute__((ext_vector_type(8)));
typedef float  f32x4  __attribute__((ext_vector_type(4)));
typedef u16    u16x8  __attribute__((ext_vector_type(8)));
typedef u16    u16x4  __attribute__((ext_vector_type(4)));

// ---------------- helpers ----------------
__device__ __forceinline__ u16 f2bf(float f) {
  union { float f; u32 u; } a; a.f = f;
  return (u16)((a.u + 0x7FFFu + ((a.u >> 16) & 1u)) >> 16);  // RNE
}
__device__ __forceinline__ float bf2f(u16 h) {
  union { u32 u; float f; } a; a.u = ((u32)h) << 16;
  return a.f;
}

__device__ __forceinline__ void gl_lds16(const u16* g, u16* l) {
  __builtin_amdgcn_global_load_lds(
      (const __attribute__((address_space(1))) void*)g,
      (__attribute__((address_space(3))) void*)l,
      16, 0, 0);
}

// ---- staging: LDS dest linear (global_load_lds requirement); XOR swizzle
// applied on the per-lane GLOBAL source chunk (rule #21), undone at read.
__device__ __forceinline__ void stage64(const u16* __restrict__ g, int ld,
                                        int row0, int k0, u16* lds, int tid) {
#pragma unroll
  for (int it = 0; it < 4; ++it) {
    int u = tid + 256 * it;        // 16B-chunk index 0..1023
    int row = u >> 3;
    int cg = (u & 7) ^ (row & 7);
    gl_lds16(g + (size_t)(row0 + row) * ld + (size_t)(k0 + cg * 8), lds + u * 8);
  }
}
__device__ __forceinline__ void stage32(const u16* __restrict__ g, int ld,
                                        int row0, int k0, u16* lds, int tid) {
#pragma unroll
  for (int it = 0; it < 2; ++it) {
    int u = tid + 256 * it;        // 16B-chunk index 0..511
    int row = u >> 2;
    int cg = (u & 3) ^ ((row >> 1) & 3);
    gl_lds16(g + (size_t)(row0 + row) * ld + (size_t)(k0 + cg * 8), lds + u * 8);
  }
}
__device__ __forceinline__ bf16x8 frag64(const u16* lds, int row, int chunk) {
  return *(const bf16x8*)(lds + row * 64 + ((chunk ^ (row & 7)) << 3));
}
__device__ __forceinline__ bf16x8 frag32(const u16* lds, int row, int chunk) {
  return *(const bf16x8*)(lds + row * 32 + ((chunk ^ ((row >> 1) & 3)) << 3));
}

#define MFMA16(c, a, b) c = __builtin_amdgcn_mfma_f32_16x16x32_bf16(a, b, c, 0, 0, 0)

// ---------------- fused prep: 3x W-transpose+split, x split ----------------
// blocks [0,768): transpose W (256 blocks each); blocks [768,2816): split x
__global__ void prep_kernel(const float* __restrict__ x,
                            const float* __restrict__ WQ,
                            const float* __restrict__ WK,
                            const float* __restrict__ WV,
                            u16* __restrict__ xh, u16* __restrict__ xl,
                            u16* __restrict__ wqh, u16* __restrict__ wql,
                            u16* __restrict__ wkh, u16* __restrict__ wkl,
                            u16* __restrict__ wvh, u16* __restrict__ wvl) {
  __shared__ float tile[64][65];
  int bx = blockIdx.x;
  if (bx < 768) {
    const float* W = (bx < 256) ? WQ : (bx < 512) ? WK : WV;
    u16* wth = (bx < 256) ? wqh : (bx < 512) ? wkh : wvh;
    u16* wtl = (bx < 256) ? wql : (bx < 512) ? wkl : wvl;
    int b = bx & 255;
    int n0 = (b & 15) * 64;
    int k0 = (b >> 4) * 64;
    int c = threadIdx.x & 63, r0 = threadIdx.x >> 6;
#pragma unroll
    for (int rr = 0; rr < 16; ++rr) {
      int r = r0 * 16 + rr;
      tile[r][c] = W[(size_t)(k0 + r) * DMODEL + n0 + c];
    }
    __syncthreads();
#pragma unroll
    for (int rr = 0; rr < 16; ++rr) {
      int n = r0 * 16 + rr;
      float f = tile[c][n];
      u16 hi = f2bf(f);
      wth[(size_t)(n0 + n) * DMODEL + k0 + c] = hi;
      wtl[(size_t)(n0 + n) * DMODEL + k0 + c] = f2bf(f - bf2f(hi));
    }
  } else {
    const int total = SEQLEN * DMODEL / 4;
    for (int idx = (bx - 768) * 256 + threadIdx.x; idx < total;
         idx += (gridDim.x - 768) * 256) {
      float4 f = ((const float4*)x)[idx];
      float ff[4] = {f.x, f.y, f.z, f.w};
      union { u16x4 v; u16 s[4]; } h, l;
#pragma unroll
      for (int uu = 0; uu < 4; ++uu) {
        u16 hi = f2bf(ff[uu]);
        h.s[uu] = hi;
        l.s[uu] = f2bf(ff[uu] - bf2f(hi));
      }
      ((u16x4*)xh)[idx] = h.v;
      ((u16x4*)xl)[idx] = l.v;
    }
  }
}

// ---------------- projection GEMM (single-buffer, high occupancy) ----------
// C = A@B^T(+bias), A=[4096][1024] hi/lo, B^T given as [n][k] hi/lo.
// THREE: 3-term split accumulation (BK=32, 32KB LDS).
// !THREE: single-term (BK=64, 32KB LDS).
template <bool THREE, bool SPLITOUT>
__global__ __launch_bounds__(256, 4) void proj_kernel(
    const u16* __restrict__ Ah, const u16* __restrict__ Al,
    const u16* __restrict__ Bh, const u16* __restrict__ Bl,
    const float* __restrict__ bias, float scale,
    u16* __restrict__ outh, u16* __restrict__ outl, u16* __restrict__ outT) {
  __shared__ __align__(16) u16 st[16384];  // 32 KB single buffer

  int tid = threadIdx.x;
  int lane = tid & 63, wid = tid >> 6;
  int wr = (wid >> 1) * 64, wc = (wid & 1) * 64;
  int r = lane & 15, g = lane >> 4;
  int m0 = blockIdx.x * 128, n0 = blockIdx.y * 128;

  f32x4 acc[4][4];
#pragma unroll
  for (int i = 0; i < 4; ++i)
#pragma unroll
    for (int j = 0; j < 4; ++j) acc[i][j] = (f32x4){0.f, 0.f, 0.f, 0.f};

  if (THREE) {
    for (int t = 0; t < DMODEL / 32; ++t) {
      int k0 = t * 32;
      __syncthreads();
      stage32(Ah, DMODEL, m0, k0, st + 0 * 4096, tid);
      stage32(Al, DMODEL, m0, k0, st + 1 * 4096, tid);
      stage32(Bh, DMODEL, n0, k0, st + 2 * 4096, tid);
      stage32(Bl, DMODEL, n0, k0, st + 3 * 4096, tid);
      __syncthreads();
      bf16x8 fa[4], fb[4], fal[4], fbl[4];
#pragma unroll
      for (int i = 0; i < 4; ++i) {
        fa[i]  = frag32(st + 0 * 4096, wr + i * 16 + r, g);
        fal[i] = frag32(st + 1 * 4096, wr + i * 16 + r, g);
        fb[i]  = frag32(st + 2 * 4096, wc + i * 16 + r, g);
        fbl[i] = frag32(st + 3 * 4096, wc + i * 16 + r, g);
      }
#pragma unroll
      for (int i = 0; i < 4; ++i)
#pragma unroll
        for (int j = 0; j < 4; ++j) {
          MFMA16(acc[i][j], fa[i], fb[j]);
          MFMA16(acc[i][j], fa[i], fbl[j]);
          MFMA16(acc[i][j], fal[i], fb[j]);
        }
    }
  } else {
    for (int t = 0; t < DMODEL / 64; ++t) {
      int k0 = t * 64;
      __syncthreads();
      stage64(Ah, DMODEL, m0, k0, st + 0 * 8192, tid);
      stage64(Bh, DMODEL, n0, k0, st + 1 * 8192, tid);
      __syncthreads();
#pragma unroll
      for (int ks = 0; ks < 2; ++ks) {
        bf16x8 fa[4], fb[4];
#pragma unroll
        for (int i = 0; i < 4; ++i) {
          fa[i] = frag64(st + 0 * 8192, wr + i * 16 + r, ks * 4 + g);
          fb[i] = frag64(st + 1 * 8192, wc + i * 16 + r, ks * 4 + g);
        }
#pragma unroll
        for (int i = 0; i < 4; ++i)
#pragma unroll
          for (int j = 0; j < 4; ++j) MFMA16(acc[i][j], fa[i], fb[j]);
      }
    }
  }

#pragma unroll
  for (int i = 0; i < 4; ++i)
#pragma unroll
    for (int j = 0; j < 4; ++j) {
      int col = n0 + wc + j * 16 + r;
      float bv = bias[col];
#pragma unroll
      for (int t = 0; t < 4; ++t) {
        int row = m0 + wr + i * 16 + g * 4 + t;
        float v = (acc[i][j][t] + bv) * scale;
        if (SPLITOUT) {
          u16 hi = f2bf(v);
          outh[(size_t)row * DMODEL + col] = hi;
          outl[(size_t)row * DMODEL + col] = f2bf(v - bf2f(hi));
        } else {
          outT[(size_t)col * SEQLEN + row] = f2bf(v);  // transposed V
        }
      }
    }
}

// ---------------- scores + in-register per-tile softmax ----------------
// S_tile = (q/32)@k^T (fp32, split-bf16 3-term); P' = exp(S - rowmax_tile)
// written bf16; per-(row,tile) max & sum stats. 32KB LDS -> 4-5 blocks/CU.
__global__ __launch_bounds__(256, 4) void scores_kernel(
    const u16* __restrict__ qh, const u16* __restrict__ ql,
    const u16* __restrict__ kh, const u16* __restrict__ kl,
    u16* __restrict__ P, float* __restrict__ mloc, float* __restrict__ tsum) {
  __shared__ __align__(16) u16 st[16384];  // 32 KB; stats alias after K-loop
  float* sm_max = (float*)st;        // [2][128]
  float* sm_sum = (float*)st + 256;  // [2][128]

  int tid = threadIdx.x;
  int lane = tid & 63, wid = tid >> 6;
  int wr = (wid >> 1) * 64, wc = (wid & 1) * 64;
  int r = lane & 15, g = lane >> 4;
  int halfid = wid & 1;
  int m0 = blockIdx.x * 128, n0 = blockIdx.y * 128;

  f32x4 acc[4][4];
#pragma unroll
  for (int i = 0; i < 4; ++i)
#pragma unroll
    for (int j = 0; j < 4; ++j) acc[i][j] = (f32x4){0.f, 0.f, 0.f, 0.f};

  for (int t = 0; t < DMODEL / 32; ++t) {
    int k0 = t * 32;
    __syncthreads();
    stage32(qh, DMODEL, m0, k0, st + 0 * 4096, tid);
    stage32(ql, DMODEL, m0, k0, st + 1 * 4096, tid);
    stage32(kh, DMODEL, n0, k0, st + 2 * 4096, tid);
    stage32(kl, DMODEL, n0, k0, st + 3 * 4096, tid);
    __syncthreads();
    bf16x8 fa[4], fb[4], fal[4], fbl[4];
#pragma unroll
    for (int i = 0; i < 4; ++i) {
      fa[i]  = frag32(st + 0 * 4096, wr + i * 16 + r, g);
      fal[i] = frag32(st + 1 * 4096, wr + i * 16 + r, g);
      fb[i]  = frag32(st + 2 * 4096, wc + i * 16 + r, g);
      fbl[i] = frag32(st + 3 * 4096, wc + i * 16 + r, g);
    }
#pragma unroll
    for (int i = 0; i < 4; ++i)
#pragma unroll
      for (int j = 0; j < 4; ++j) {
        MFMA16(acc[i][j], fa[i], fb[j]);
        MFMA16(acc[i][j], fa[i], fbl[j]);
        MFMA16(acc[i][j], fal[i], fb[j]);
      }
  }

  // ---- in-register softmax over this 128-col tile ----
  __syncthreads();  // all staging reads done; safe to alias stats over st

  // per-row max over this wave's 64 cols: reduce over j then over 16-lane group
#pragma unroll
  for (int i = 0; i < 4; ++i)
#pragma unroll
    for (int t = 0; t < 4; ++t) {
      float m = fmaxf(fmaxf(acc[i][0][t], acc[i][1][t]),
                      fmaxf(acc[i][2][t], acc[i][3][t]));
      m = fmaxf(m, __shfl_xor(m, 1));
      m = fmaxf(m, __shfl_xor(m, 2));
      m = fmaxf(m, __shfl_xor(m, 4));
      m = fmaxf(m, __shfl_xor(m, 8));
      if (r == 0) sm_max[halfid * 128 + wr + i * 16 + g * 4 + t] = m;
    }
  __syncthreads();

  // combine halves, exponentiate, store P', accumulate row sums
#pragma unroll
  for (int i = 0; i < 4; ++i)
#pragma unroll
    for (int t = 0; t < 4; ++t) {
      int R = wr + i * 16 + g * 4 + t;
      float mx = fmaxf(sm_max[R], sm_max[128 + R]);
      u16* pout = P + (size_t)(m0 + R) * SEQLEN + n0 + wc + r;
      float lsum = 0.f;
#pragma unroll
      for (int j = 0; j < 4; ++j) {
        float e = exp2f((acc[i][j][t] - mx) * 1.4426950408889634f);
        lsum += e;
        pout[j * 16] = f2bf(e);
      }
      lsum += __shfl_xor(lsum, 1);
      lsum += __shfl_xor(lsum, 2);
      lsum += __shfl_xor(lsum, 4);
      lsum += __shfl_xor(lsum, 8);
      if (r == 0) sm_sum[halfid * 128 + R] = lsum;
    }
  __syncthreads();

  if (halfid == 0 && r == 0) {
#pragma unroll
    for (int i = 0; i < 4; ++i)
#pragma unroll
      for (int t = 0; t < 4; ++t) {
        int R = wr + i * 16 + g * 4 + t;
        int grow = m0 + R;
        mloc[(size_t)blockIdx.y * SEQLEN + grow] =
            fmaxf(sm_max[R], sm_max[128 + R]);
        tsum[(size_t)blockIdx.y * SEQLEN + grow] = sm_sum[R] + sm_sum[128 + R];
      }
  }
}

// ---------------- softmax finalize ----------------
__global__ void finalize_kernel(const float* __restrict__ mloc,
                                const float* __restrict__ tsum,
                                float* __restrict__ rowscale) {
  int rr = blockIdx.x * 256 + threadIdx.x;
  if (rr >= SEQLEN) return;
  float M = -3.0e38f;
#pragma unroll
  for (int t = 0; t < 32; ++t) M = fmaxf(M, mloc[t * SEQLEN + rr]);
  float l = 0.f;
#pragma unroll
  for (int t = 0; t < 32; ++t)
    l += tsum[t * SEQLEN + rr] * exp2f((mloc[t * SEQLEN + rr] - M) * 1.4426950408889634f);
  float inv = 1.0f / l;
#pragma unroll
  for (int t = 0; t < 32; ++t)
    rowscale[t * SEQLEN + rr] = exp2f((mloc[t * SEQLEN + rr] - M) * 1.4426950408889634f) * inv;
}

// ---------------- PV GEMM with fused softmax rescale ----------------
// out[m][n] = sum_c rowscale[c][m] * (P'_c @ V_c)[m][n]  (c = 128-col chunks)
__global__ __launch_bounds__(256, 3) void pv_kernel(
    const u16* __restrict__ P, const u16* __restrict__ vT,
    const float* __restrict__ rowscale, float* __restrict__ out) {
  __shared__ __align__(16) u16 st[16384];  // 32 KB single buffer
  int tid = threadIdx.x;
  int lane = tid & 63, wid = tid >> 6;
  int wr = (wid >> 1) * 64, wc = (wid & 1) * 64;
  int r = lane & 15, g = lane >> 4;
  int m0 = blockIdx.x * 128, n0 = blockIdx.y * 128;

  f32x4 acc[4][4];
#pragma unroll
  for (int i = 0; i < 4; ++i)
#pragma unroll
    for (int j = 0; j < 4; ++j) acc[i][j] = (f32x4){0.f, 0.f, 0.f, 0.f};

  for (int c = 0; c < SEQLEN / 128; ++c) {
    f32x4 rs[4];
#pragma unroll
    for (int i = 0; i < 4; ++i)
      rs[i] = *(const f32x4*)&rowscale[(size_t)c * SEQLEN + m0 + wr + i * 16 + g * 4];
    f32x4 part[4][4];
#pragma unroll
    for (int i = 0; i < 4; ++i)
#pragma unroll
      for (int j = 0; j < 4; ++j) part[i][j] = (f32x4){0.f, 0.f, 0.f, 0.f};
#pragma unroll
    for (int s2 = 0; s2 < 2; ++s2) {
      int k0 = c * 128 + s2 * 64;
      __syncthreads();
      stage64(P, SEQLEN, m0, k0, st + 0 * 8192, tid);
      stage64(vT, SEQLEN, n0, k0, st + 1 * 8192, tid);
      __syncthreads();
#pragma unroll
      for (int ks = 0; ks < 2; ++ks) {
        bf16x8 fa[4], fb[4];
#pragma unroll
        for (int i = 0; i < 4; ++i) {
          fa[i] = frag64(st + 0 * 8192, wr + i * 16 + r, ks * 4 + g);
          fb[i] = frag64(st + 1 * 8192, wc + i * 16 + r, ks * 4 + g);
        }
#pragma unroll
        for (int i = 0; i < 4; ++i)
#pragma unroll
          for (int j = 0; j < 4; ++j) MFMA16(part[i][j], fa[i], fb[j]);
      }
    }
#pragma unroll
    for (int i = 0; i < 4; ++i)
#pragma unroll
      for (int j = 0; j < 4; ++j) part[i][j] = part[i][j] * rs[i], acc[i][j] += part[i][j];
  }
#pragma unroll
  for (int i = 0; i < 4; ++i)
#pragma unroll
    for (int j = 0; j < 4; ++j)
#pragma unroll
      for (int t = 0; t < 4; ++t)
        out[(size_t)(m0 + wr + i * 16 + g * 4 + t) * DMODEL + n0 + wc + j * 16 + r] =
            acc[i][j][t];
}

// ---------------- launch ----------------
extern "C" void kernel_launch(void* const* d_in, const int* in_sizes, int n_in,
                              void* d_out, int out_size, void* d_ws, size_t ws_size,
                              hipStream_t stream) {
  (void)in_sizes; (void)n_in; (void)out_size; (void)ws_size;
  const float* x  = (const float*)d_in[0];
  const float* WQ = (const float*)d_in[1];
  const float* WK = (const float*)d_in[2];
  const float* WV = (const float*)d_in[3];
  const float* bQ = (const float*)d_in[4];
  const float* bK = (const float*)d_in[5];
  const float* bV = (const float*)d_in[6];
  float* out = (float*)d_out;
  char* ws = (char*)d_ws;
  const size_t MB = 1ull << 20;

  // Prep region [0,28MB) is dead after projections; P (32MB) overlays it.
  u16* xh   = (u16*)(ws + 0);
  u16* xl   = (u16*)(ws + 8 * MB);
  u16* wqh  = (u16*)(ws + 16 * MB);
  u16* wql  = (u16*)(ws + 18 * MB);
  u16* wkh  = (u16*)(ws + 20 * MB);
  u16* wkl  = (u16*)(ws + 22 * MB);
  u16* wvh  = (u16*)(ws + 24 * MB);
  u16* wvl  = (u16*)(ws + 26 * MB);
  u16* P    = (u16*)(ws + 0);  // 32MB, written after prep region is dead
  u16* qh   = (u16*)(ws + 32 * MB);
  u16* ql   = (u16*)(ws + 40 * MB);
  u16* kh   = (u16*)(ws + 48 * MB);
  u16* kl   = (u16*)(ws + 56 * MB);
  u16* vT   = (u16*)(ws + 64 * MB);
  float* mloc     = (float*)(ws + 72 * MB);
  float* tsum     = (float*)(ws + 72 * MB + 512 * 1024);
  float* rowscale = (float*)(ws + 73 * MB);

  prep_kernel<<<2816, 256, 0, stream>>>(x, WQ, WK, WV, xh, xl, wqh, wql,
                                        wkh, wkl, wvh, wvl);

  dim3 gproj(32, 8);
  // Q: scaled by 1/sqrt(D)=1/32 before split; K: unscaled; both split hi/lo.
  proj_kernel<true, true><<<gproj, 256, 0, stream>>>(xh, xl, wqh, wql, bQ,
                                                     1.0f / 32.0f, qh, ql, nullptr);
  proj_kernel<true, true><<<gproj, 256, 0, stream>>>(xh, xl, wkh, wkl, bK,
                                                     1.0f, kh, kl, nullptr);
  // V: single-term bf16 is accurate enough; written transposed for PV.
  proj_kernel<false, false><<<gproj, 256, 0, stream>>>(xh, nullptr, wvh, nullptr, bV,
                                                       1.0f, nullptr, nullptr, vT);

  dim3 gsc(32, 32);
  scores_kernel<<<gsc, 256, 0, stream>>>(qh, ql, kh, kl, P, mloc, tsum);
  finalize_kernel<<<16, 256, 0, stream>>>(mloc, tsum, rowscale);

  dim3 gpv(32, 8);
  pv_kernel<<<gpv, 256, 0, stream>>>(P, vT, rowscale, out);
}

// Round 6
// 372.755 us; speedup vs baseline: 1.2935x; 1.2935x over previous
//
#include <hip/hip_runtime.h>
#include <hip/hip_bf16.h>
#include <stdint.h>

#define SEQLEN 4096
#define DMODEL 1024

typedef uint16_t u16;
typedef uint32_t u32;

typedef __bf16 bf16x8 __attribute__((ext_vector_type(8)));
typedef float  f32x4  __attribute__((ext_vector_type(4)));
typedef u16    u16x8  __attribute__((ext_vector_type(8)));
typedef u16    u16x4  __attribute__((ext_vector_type(4)));

// ---------------- helpers ----------------
__device__ __forceinline__ u16 f2bf(float f) {
  union { float f; u32 u; } a; a.f = f;
  return (u16)((a.u + 0x7FFFu + ((a.u >> 16) & 1u)) >> 16);  // RNE
}
__device__ __forceinline__ float bf2f(u16 h) {
  union { u32 u; float f; } a; a.u = ((u32)h) << 16;
  return a.f;
}

__device__ __forceinline__ void gl_lds16(const u16* g, u16* l) {
  __builtin_amdgcn_global_load_lds(
      (const __attribute__((address_space(1))) void*)g,
      (__attribute__((address_space(3))) void*)l,
      16, 0, 0);
}

// ---- staging: LDS dest linear (global_load_lds requirement); XOR swizzle
// applied on the per-lane GLOBAL source chunk (rule #21), undone at read.
__device__ __forceinline__ void stage64(const u16* __restrict__ g, int ld,
                                        int row0, int k0, u16* lds, int tid) {
#pragma unroll
  for (int it = 0; it < 4; ++it) {
    int u = tid + 256 * it;        // 16B-chunk index 0..1023
    int row = u >> 3;
    int cg = (u & 7) ^ (row & 7);
    gl_lds16(g + (size_t)(row0 + row) * ld + (size_t)(k0 + cg * 8), lds + u * 8);
  }
}
__device__ __forceinline__ void stage32(const u16* __restrict__ g, int ld,
                                        int row0, int k0, u16* lds, int tid) {
#pragma unroll
  for (int it = 0; it < 2; ++it) {
    int u = tid + 256 * it;        // 16B-chunk index 0..511
    int row = u >> 2;
    int cg = (u & 3) ^ ((row >> 1) & 3);
    gl_lds16(g + (size_t)(row0 + row) * ld + (size_t)(k0 + cg * 8), lds + u * 8);
  }
}
__device__ __forceinline__ bf16x8 frag64(const u16* lds, int row, int chunk) {
  return *(const bf16x8*)(lds + row * 64 + ((chunk ^ (row & 7)) << 3));
}
__device__ __forceinline__ bf16x8 frag32(const u16* lds, int row, int chunk) {
  return *(const bf16x8*)(lds + row * 32 + ((chunk ^ ((row >> 1) & 3)) << 3));
}

#define MFMA16(c, a, b) c = __builtin_amdgcn_mfma_f32_16x16x32_bf16(a, b, c, 0, 0, 0)

// ---------------- fused prep: 3x W-transpose+split, x split ----------------
__global__ void prep_kernel(const float* __restrict__ x,
                            const float* __restrict__ WQ,
                            const float* __restrict__ WK,
                            const float* __restrict__ WV,
                            u16* __restrict__ xh, u16* __restrict__ xl,
                            u16* __restrict__ wqh, u16* __restrict__ wql,
                            u16* __restrict__ wkh, u16* __restrict__ wkl,
                            u16* __restrict__ wvh, u16* __restrict__ wvl) {
  __shared__ float tile[64][65];
  int bx = blockIdx.x;
  if (bx < 768) {
    const float* W = (bx < 256) ? WQ : (bx < 512) ? WK : WV;
    u16* wth = (bx < 256) ? wqh : (bx < 512) ? wkh : wvh;
    u16* wtl = (bx < 256) ? wql : (bx < 512) ? wkl : wvl;
    int b = bx & 255;
    int n0 = (b & 15) * 64;
    int k0 = (b >> 4) * 64;
    int c = threadIdx.x & 63, r0 = threadIdx.x >> 6;
#pragma unroll
    for (int rr = 0; rr < 16; ++rr) {
      int r = r0 * 16 + rr;
      tile[r][c] = W[(size_t)(k0 + r) * DMODEL + n0 + c];
    }
    __syncthreads();
#pragma unroll
    for (int rr = 0; rr < 16; ++rr) {
      int n = r0 * 16 + rr;
      float f = tile[c][n];
      u16 hi = f2bf(f);
      wth[(size_t)(n0 + n) * DMODEL + k0 + c] = hi;
      wtl[(size_t)(n0 + n) * DMODEL + k0 + c] = f2bf(f - bf2f(hi));
    }
  } else {
    const int total = SEQLEN * DMODEL / 4;
    for (int idx = (bx - 768) * 256 + threadIdx.x; idx < total;
         idx += (gridDim.x - 768) * 256) {
      float4 f = ((const float4*)x)[idx];
      float ff[4] = {f.x, f.y, f.z, f.w};
      union { u16x4 v; u16 s[4]; } h, l;
#pragma unroll
      for (int uu = 0; uu < 4; ++uu) {
        u16 hi = f2bf(ff[uu]);
        h.s[uu] = hi;
        l.s[uu] = f2bf(ff[uu] - bf2f(hi));
      }
      ((u16x4*)xh)[idx] = h.v;
      ((u16x4*)xl)[idx] = l.v;
    }
  }
}

// ---------------- projection GEMM (single-buffer, high occupancy) ----------
template <bool THREE, bool SPLITOUT>
__global__ __launch_bounds__(256, 4) void proj_kernel(
    const u16* __restrict__ Ah, const u16* __restrict__ Al,
    const u16* __restrict__ Bh, const u16* __restrict__ Bl,
    const float* __restrict__ bias, float scale,
    u16* __restrict__ outh, u16* __restrict__ outl, u16* __restrict__ outT) {
  __shared__ __align__(16) u16 st[16384];  // 32 KB single buffer

  int tid = threadIdx.x;
  int lane = tid & 63, wid = tid >> 6;
  int wr = (wid >> 1) * 64, wc = (wid & 1) * 64;
  int r = lane & 15, g = lane >> 4;
  int m0 = blockIdx.x * 128, n0 = blockIdx.y * 128;

  f32x4 acc[4][4];
#pragma unroll
  for (int i = 0; i < 4; ++i)
#pragma unroll
    for (int j = 0; j < 4; ++j) acc[i][j] = (f32x4){0.f, 0.f, 0.f, 0.f};

  if (THREE) {
    for (int t = 0; t < DMODEL / 32; ++t) {
      int k0 = t * 32;
      __syncthreads();
      stage32(Ah, DMODEL, m0, k0, st + 0 * 4096, tid);
      stage32(Al, DMODEL, m0, k0, st + 1 * 4096, tid);
      stage32(Bh, DMODEL, n0, k0, st + 2 * 4096, tid);
      stage32(Bl, DMODEL, n0, k0, st + 3 * 4096, tid);
      __syncthreads();
      bf16x8 fa[4], fb[4], fal[4], fbl[4];
#pragma unroll
      for (int i = 0; i < 4; ++i) {
        fa[i]  = frag32(st + 0 * 4096, wr + i * 16 + r, g);
        fal[i] = frag32(st + 1 * 4096, wr + i * 16 + r, g);
        fb[i]  = frag32(st + 2 * 4096, wc + i * 16 + r, g);
        fbl[i] = frag32(st + 3 * 4096, wc + i * 16 + r, g);
      }
#pragma unroll
      for (int i = 0; i < 4; ++i)
#pragma unroll
        for (int j = 0; j < 4; ++j) {
          MFMA16(acc[i][j], fa[i], fb[j]);
          MFMA16(acc[i][j], fa[i], fbl[j]);
          MFMA16(acc[i][j], fal[i], fb[j]);
        }
    }
  } else {
    for (int t = 0; t < DMODEL / 64; ++t) {
      int k0 = t * 64;
      __syncthreads();
      stage64(Ah, DMODEL, m0, k0, st + 0 * 8192, tid);
      stage64(Bh, DMODEL, n0, k0, st + 1 * 8192, tid);
      __syncthreads();
#pragma unroll
      for (int ks = 0; ks < 2; ++ks) {
        bf16x8 fa[4], fb[4];
#pragma unroll
        for (int i = 0; i < 4; ++i) {
          fa[i] = frag64(st + 0 * 8192, wr + i * 16 + r, ks * 4 + g);
          fb[i] = frag64(st + 1 * 8192, wc + i * 16 + r, ks * 4 + g);
        }
#pragma unroll
        for (int i = 0; i < 4; ++i)
#pragma unroll
          for (int j = 0; j < 4; ++j) MFMA16(acc[i][j], fa[i], fb[j]);
      }
    }
  }

#pragma unroll
  for (int i = 0; i < 4; ++i)
#pragma unroll
    for (int j = 0; j < 4; ++j) {
      int col = n0 + wc + j * 16 + r;
      float bv = bias[col];
#pragma unroll
      for (int t = 0; t < 4; ++t) {
        int row = m0 + wr + i * 16 + g * 4 + t;
        float v = (acc[i][j][t] + bv) * scale;
        if (SPLITOUT) {
          u16 hi = f2bf(v);
          outh[(size_t)row * DMODEL + col] = hi;
          outl[(size_t)row * DMODEL + col] = f2bf(v - bf2f(hi));
        } else {
          outT[(size_t)col * SEQLEN + row] = f2bf(v);  // transposed V
        }
      }
    }
}

// ---------------- scores + in-register per-tile softmax ----------------
// S_tile = (q/32)@k^T (fp32, split-bf16 3-term); P' = exp(S - rowmax_tile)
// repacked through LDS for coalesced bf16 stores; per-(row,tile) max & sum.
__global__ __launch_bounds__(256, 4) void scores_kernel(
    const u16* __restrict__ qh, const u16* __restrict__ ql,
    const u16* __restrict__ kh, const u16* __restrict__ kl,
    u16* __restrict__ P, float* __restrict__ mloc, float* __restrict__ tsum) {
  __shared__ __align__(16) u16 st[16384];  // 32 KB: staging, then P-tile
  __shared__ float sm_max[256];            // [2][128]
  __shared__ float sm_sum[256];

  int tid = threadIdx.x;
  int lane = tid & 63, wid = tid >> 6;
  int wr = (wid >> 1) * 64, wc = (wid & 1) * 64;
  int r = lane & 15, g = lane >> 4;
  int halfid = wid & 1;
  int m0 = blockIdx.x * 128, n0 = blockIdx.y * 128;

  f32x4 acc[4][4];
#pragma unroll
  for (int i = 0; i < 4; ++i)
#pragma unroll
    for (int j = 0; j < 4; ++j) acc[i][j] = (f32x4){0.f, 0.f, 0.f, 0.f};

  for (int t = 0; t < DMODEL / 32; ++t) {
    int k0 = t * 32;
    __syncthreads();
    stage32(qh, DMODEL, m0, k0, st + 0 * 4096, tid);
    stage32(ql, DMODEL, m0, k0, st + 1 * 4096, tid);
    stage32(kh, DMODEL, n0, k0, st + 2 * 4096, tid);
    stage32(kl, DMODEL, n0, k0, st + 3 * 4096, tid);
    __syncthreads();
    bf16x8 fa[4], fb[4], fal[4], fbl[4];
#pragma unroll
    for (int i = 0; i < 4; ++i) {
      fa[i]  = frag32(st + 0 * 4096, wr + i * 16 + r, g);
      fal[i] = frag32(st + 1 * 4096, wr + i * 16 + r, g);
      fb[i]  = frag32(st + 2 * 4096, wc + i * 16 + r, g);
      fbl[i] = frag32(st + 3 * 4096, wc + i * 16 + r, g);
    }
#pragma unroll
    for (int i = 0; i < 4; ++i)
#pragma unroll
      for (int j = 0; j < 4; ++j) {
        MFMA16(acc[i][j], fa[i], fb[j]);
        MFMA16(acc[i][j], fa[i], fbl[j]);
        MFMA16(acc[i][j], fal[i], fb[j]);
      }
  }

  __syncthreads();  // staging reads done; st becomes the bf16 P-tile

  // per-row max over this wave's 64 cols, exchanged via sm_max
#pragma unroll
  for (int i = 0; i < 4; ++i)
#pragma unroll
    for (int t = 0; t < 4; ++t) {
      float m = fmaxf(fmaxf(acc[i][0][t], acc[i][1][t]),
                      fmaxf(acc[i][2][t], acc[i][3][t]));
      m = fmaxf(m, __shfl_xor(m, 1));
      m = fmaxf(m, __shfl_xor(m, 2));
      m = fmaxf(m, __shfl_xor(m, 4));
      m = fmaxf(m, __shfl_xor(m, 8));
      if (r == 0) sm_max[halfid * 128 + wr + i * 16 + g * 4 + t] = m;
    }
  __syncthreads();

  // exponentiate, write bf16 P-tile into LDS (XOR-swizzled), row sums
#pragma unroll
  for (int i = 0; i < 4; ++i)
#pragma unroll
    for (int t = 0; t < 4; ++t) {
      int R = wr + i * 16 + g * 4 + t;
      float mx = fmaxf(sm_max[R], sm_max[128 + R]);
      int sw = ((R >> 2) & 3) << 5;  // XOR bits 5-6 of col, varies per g
      float lsum = 0.f;
#pragma unroll
      for (int j = 0; j < 4; ++j) {
        float e = exp2f((acc[i][j][t] - mx) * 1.4426950408889634f);
        lsum += e;
        st[R * 128 + ((wc + j * 16 + r) ^ sw)] = f2bf(e);
      }
      lsum += __shfl_xor(lsum, 1);
      lsum += __shfl_xor(lsum, 2);
      lsum += __shfl_xor(lsum, 4);
      lsum += __shfl_xor(lsum, 8);
      if (r == 0) sm_sum[halfid * 128 + R] = lsum;
    }
  __syncthreads();

  // coalesced P write: 2048 16B-chunks, undoing the swizzle
#pragma unroll
  for (int k = 0; k < 8; ++k) {
    int cidx = k * 256 + tid;       // 0..2047
    int rrow = cidx >> 4;           // 16 chunks per row
    int col0 = (cidx & 15) * 8;
    int sw = ((rrow >> 2) & 3) << 5;
    u16x8 v = *(const u16x8*)(st + rrow * 128 + (col0 ^ sw));
    *(u16x8*)(P + (size_t)(m0 + rrow) * SEQLEN + n0 + col0) = v;
  }

  if (halfid == 0 && r == 0) {
#pragma unroll
    for (int i = 0; i < 4; ++i)
#pragma unroll
      for (int t = 0; t < 4; ++t) {
        int R = wr + i * 16 + g * 4 + t;
        int grow = m0 + R;
        mloc[(size_t)blockIdx.y * SEQLEN + grow] =
            fmaxf(sm_max[R], sm_max[128 + R]);
        tsum[(size_t)blockIdx.y * SEQLEN + grow] = sm_sum[R] + sm_sum[128 + R];
      }
  }
}

// ---------------- softmax finalize ----------------
__global__ void finalize_kernel(const float* __restrict__ mloc,
                                const float* __restrict__ tsum,
                                float* __restrict__ rowscale) {
  int rr = blockIdx.x * 256 + threadIdx.x;
  if (rr >= SEQLEN) return;
  float M = -3.0e38f;
#pragma unroll
  for (int t = 0; t < 32; ++t) M = fmaxf(M, mloc[t * SEQLEN + rr]);
  float l = 0.f;
#pragma unroll
  for (int t = 0; t < 32; ++t)
    l += tsum[t * SEQLEN + rr] * exp2f((mloc[t * SEQLEN + rr] - M) * 1.4426950408889634f);
  float inv = 1.0f / l;
#pragma unroll
  for (int t = 0; t < 32; ++t)
    rowscale[t * SEQLEN + rr] = exp2f((mloc[t * SEQLEN + rr] - M) * 1.4426950408889634f) * inv;
}

__global__ void pnorm_kernel(u16* __restrict__ P, const float* __restrict__ rowscale) {
  const int total = SEQLEN * SEQLEN / 8;
  for (int idx = blockIdx.x * 256 + threadIdx.x; idx < total; idx += gridDim.x * 256) {
    int rrow = idx >> 9;
    int c8 = idx & 511;
    int t = c8 >> 4;
    float sc = rowscale[t * SEQLEN + rrow];
    union { u16x8 v; u16 s[8]; } d;
    d.v = ((u16x8*)P)[idx];
#pragma unroll
    for (int uu = 0; uu < 8; ++uu) d.s[uu] = f2bf(bf2f(d.s[uu]) * sc);
    ((u16x8*)P)[idx] = d.v;
  }
}

// ---------------- PV GEMM (plain, high occupancy) ----------------
__global__ __launch_bounds__(256, 4) void pv_kernel(const u16* __restrict__ P,
                                                    const u16* __restrict__ vT,
                                                    float* __restrict__ out) {
  __shared__ __align__(16) u16 st[16384];  // 32 KB single buffer
  int tid = threadIdx.x;
  int lane = tid & 63, wid = tid >> 6;
  int wr = (wid >> 1) * 64, wc = (wid & 1) * 64;
  int r = lane & 15, g = lane >> 4;
  int m0 = blockIdx.x * 128, n0 = blockIdx.y * 128;

  f32x4 acc[4][4];
#pragma unroll
  for (int i = 0; i < 4; ++i)
#pragma unroll
    for (int j = 0; j < 4; ++j) acc[i][j] = (f32x4){0.f, 0.f, 0.f, 0.f};

  for (int t = 0; t < SEQLEN / 64; ++t) {
    int k0 = t * 64;
    __syncthreads();
    stage64(P, SEQLEN, m0, k0, st + 0 * 8192, tid);
    stage64(vT, SEQLEN, n0, k0, st + 1 * 8192, tid);
    __syncthreads();
#pragma unroll
    for (int ks = 0; ks < 2; ++ks) {
      bf16x8 fa[4], fb[4];
#pragma unroll
      for (int i = 0; i < 4; ++i) {
        fa[i] = frag64(st + 0 * 8192, wr + i * 16 + r, ks * 4 + g);
        fb[i] = frag64(st + 1 * 8192, wc + i * 16 + r, ks * 4 + g);
      }
#pragma unroll
      for (int i = 0; i < 4; ++i)
#pragma unroll
        for (int j = 0; j < 4; ++j) MFMA16(acc[i][j], fa[i], fb[j]);
    }
  }
#pragma unroll
  for (int i = 0; i < 4; ++i)
#pragma unroll
    for (int j = 0; j < 4; ++j)
#pragma unroll
      for (int t = 0; t < 4; ++t)
        out[(size_t)(m0 + wr + i * 16 + g * 4 + t) * DMODEL + n0 + wc + j * 16 + r] =
            acc[i][j][t];
}

// ---------------- launch ----------------
extern "C" void kernel_launch(void* const* d_in, const int* in_sizes, int n_in,
                              void* d_out, int out_size, void* d_ws, size_t ws_size,
                              hipStream_t stream) {
  (void)in_sizes; (void)n_in; (void)out_size; (void)ws_size;
  const float* x  = (const float*)d_in[0];
  const float* WQ = (const float*)d_in[1];
  const float* WK = (const float*)d_in[2];
  const float* WV = (const float*)d_in[3];
  const float* bQ = (const float*)d_in[4];
  const float* bK = (const float*)d_in[5];
  const float* bV = (const float*)d_in[6];
  float* out = (float*)d_out;
  char* ws = (char*)d_ws;
  const size_t MB = 1ull << 20;

  // Prep region [0,28MB) is dead after projections; P (32MB) overlays it.
  u16* xh   = (u16*)(ws + 0);
  u16* xl   = (u16*)(ws + 8 * MB);
  u16* wqh  = (u16*)(ws + 16 * MB);
  u16* wql  = (u16*)(ws + 18 * MB);
  u16* wkh  = (u16*)(ws + 20 * MB);
  u16* wkl  = (u16*)(ws + 22 * MB);
  u16* wvh  = (u16*)(ws + 24 * MB);
  u16* wvl  = (u16*)(ws + 26 * MB);
  u16* P    = (u16*)(ws + 0);  // 32MB, written after prep region is dead
  u16* qh   = (u16*)(ws + 32 * MB);
  u16* ql   = (u16*)(ws + 40 * MB);
  u16* kh   = (u16*)(ws + 48 * MB);
  u16* kl   = (u16*)(ws + 56 * MB);
  u16* vT   = (u16*)(ws + 64 * MB);
  float* mloc     = (float*)(ws + 72 * MB);
  float* tsum     = (float*)(ws + 72 * MB + 512 * 1024);
  float* rowscale = (float*)(ws + 73 * MB);

  prep_kernel<<<2816, 256, 0, stream>>>(x, WQ, WK, WV, xh, xl, wqh, wql,
                                        wkh, wkl, wvh, wvl);

  dim3 gproj(32, 8);
  proj_kernel<true, true><<<gproj, 256, 0, stream>>>(xh, xl, wqh, wql, bQ,
                                                     1.0f / 32.0f, qh, ql, nullptr);
  proj_kernel<true, true><<<gproj, 256, 0, stream>>>(xh, xl, wkh, wkl, bK,
                                                     1.0f, kh, kl, nullptr);
  proj_kernel<false, false><<<gproj, 256, 0, stream>>>(xh, nullptr, wvh, nullptr, bV,
                                                       1.0f, nullptr, nullptr, vT);

  dim3 gsc(32, 32);
  scores_kernel<<<gsc, 256, 0, stream>>>(qh, ql, kh, kl, P, mloc, tsum);
  finalize_kernel<<<16, 256, 0, stream>>>(mloc, tsum, rowscale);
  pnorm_kernel<<<4096, 256, 0, stream>>>(P, rowscale);

  dim3 gpv(32, 8);
  pv_kernel<<<gpv, 256, 0, stream>>>(P, vT, out);
}

// Round 7
// 359.650 us; speedup vs baseline: 1.3407x; 1.0364x over previous
//
#include <hip/hip_runtime.h>
#include <hip/hip_bf16.h>
#include <stdint.h>

#define SEQLEN 4096
#define DMODEL 1024

typedef uint16_t u16;
typedef uint32_t u32;

typedef __bf16 bf16x8 __attribute__((ext_vector_type(8)));
typedef float  f32x4  __attribute__((ext_vector_type(4)));
typedef u16    u16x8  __attribute__((ext_vector_type(8)));
typedef u16    u16x4  __attribute__((ext_vector_type(4)));

#define VMCNT0() asm volatile("s_waitcnt vmcnt(0)" ::: "memory")
#define BAR() __builtin_amdgcn_s_barrier()

// ---------------- helpers ----------------
__device__ __forceinline__ u16 f2bf(float f) {
  union { float f; u32 u; } a; a.f = f;
  return (u16)((a.u + 0x7FFFu + ((a.u >> 16) & 1u)) >> 16);  // RNE
}
__device__ __forceinline__ float bf2f(u16 h) {
  union { u32 u; float f; } a; a.u = ((u32)h) << 16;
  return a.f;
}

union U8 { bf16x8 v; u16 s[8]; };
__device__ __forceinline__ bf16x8 scale8(bf16x8 a, float s) {
  U8 in, out; in.v = a;
#pragma unroll
  for (int e = 0; e < 8; ++e) out.s[e] = f2bf(bf2f(in.s[e]) * s);
  return out.v;
}

__device__ __forceinline__ void gl_lds16(const u16* g, u16* l) {
  __builtin_amdgcn_global_load_lds(
      (const __attribute__((address_space(1))) void*)g,
      (__attribute__((address_space(3))) void*)l,
      16, 0, 0);
}

// ---- staging: LDS dest linear (global_load_lds requirement); XOR swizzle
// applied on the per-lane GLOBAL source chunk (rule #21), undone at read.
__device__ __forceinline__ void stage64(const u16* __restrict__ g, int ld,
                                        int row0, int k0, u16* lds, int tid) {
#pragma unroll
  for (int it = 0; it < 4; ++it) {
    int u = tid + 256 * it;        // 16B-chunk index 0..1023
    int row = u >> 3;
    int cg = (u & 7) ^ (row & 7);
    gl_lds16(g + (size_t)(row0 + row) * ld + (size_t)(k0 + cg * 8), lds + u * 8);
  }
}
__device__ __forceinline__ void stage32(const u16* __restrict__ g, int ld,
                                        int row0, int k0, u16* lds, int tid) {
#pragma unroll
  for (int it = 0; it < 2; ++it) {
    int u = tid + 256 * it;        // 16B-chunk index 0..511
    int row = u >> 2;
    int cg = (u & 3) ^ ((row >> 1) & 3);
    gl_lds16(g + (size_t)(row0 + row) * ld + (size_t)(k0 + cg * 8), lds + u * 8);
  }
}
__device__ __forceinline__ bf16x8 frag64(const u16* lds, int row, int chunk) {
  return *(const bf16x8*)(lds + row * 64 + ((chunk ^ (row & 7)) << 3));
}
__device__ __forceinline__ bf16x8 frag32(const u16* lds, int row, int chunk) {
  return *(const bf16x8*)(lds + row * 32 + ((chunk ^ ((row >> 1) & 3)) << 3));
}

#define MFMA16(c, a, b) c = __builtin_amdgcn_mfma_f32_16x16x32_bf16(a, b, c, 0, 0, 0)

// ---------------- fused prep: 3x W-transpose+split, x split ----------------
__global__ void prep_kernel(const float* __restrict__ x,
                            const float* __restrict__ WQ,
                            const float* __restrict__ WK,
                            const float* __restrict__ WV,
                            u16* __restrict__ xh, u16* __restrict__ xl,
                            u16* __restrict__ wqh, u16* __restrict__ wql,
                            u16* __restrict__ wkh, u16* __restrict__ wkl,
                            u16* __restrict__ wvh, u16* __restrict__ wvl) {
  __shared__ float tile[64][65];
  int bx = blockIdx.x;
  if (bx < 768) {
    const float* W = (bx < 256) ? WQ : (bx < 512) ? WK : WV;
    u16* wth = (bx < 256) ? wqh : (bx < 512) ? wkh : wvh;
    u16* wtl = (bx < 256) ? wql : (bx < 512) ? wkl : wvl;
    int b = bx & 255;
    int n0 = (b & 15) * 64;
    int k0 = (b >> 4) * 64;
    int c = threadIdx.x & 63, r0 = threadIdx.x >> 6;
#pragma unroll
    for (int rr = 0; rr < 16; ++rr) {
      int r = r0 * 16 + rr;
      tile[r][c] = W[(size_t)(k0 + r) * DMODEL + n0 + c];
    }
    __syncthreads();
#pragma unroll
    for (int rr = 0; rr < 16; ++rr) {
      int n = r0 * 16 + rr;
      float f = tile[c][n];
      u16 hi = f2bf(f);
      wth[(size_t)(n0 + n) * DMODEL + k0 + c] = hi;
      wtl[(size_t)(n0 + n) * DMODEL + k0 + c] = f2bf(f - bf2f(hi));
    }
  } else {
    const int total = SEQLEN * DMODEL / 4;
    for (int idx = (bx - 768) * 256 + threadIdx.x; idx < total;
         idx += (gridDim.x - 768) * 256) {
      float4 f = ((const float4*)x)[idx];
      float ff[4] = {f.x, f.y, f.z, f.w};
      union { u16x4 v; u16 s[4]; } h, l;
#pragma unroll
      for (int uu = 0; uu < 4; ++uu) {
        u16 hi = f2bf(ff[uu]);
        h.s[uu] = hi;
        l.s[uu] = f2bf(ff[uu] - bf2f(hi));
      }
      ((u16x4*)xh)[idx] = h.v;
      ((u16x4*)xl)[idx] = l.v;
    }
  }
}

// ---------------- projection GEMM (T3-minimum 2-phase pipeline) ------------
// C = A@B^T(+bias). THREE: 3-term split accumulation (BK=32).
// !THREE: single-term (BK=64). Both: 64KB double-buffered LDS, occ 2.
template <bool THREE, bool SPLITOUT>
__global__ __launch_bounds__(256, 2) void proj_kernel(
    const u16* __restrict__ Ah, const u16* __restrict__ Al,
    const u16* __restrict__ Bh, const u16* __restrict__ Bl,
    const float* __restrict__ bias, float scale,
    u16* __restrict__ outh, u16* __restrict__ outl, u16* __restrict__ outT) {
  __shared__ __align__(16) u16 st[32768];  // 64 KB: 2 buffers of 16384

  int tid = threadIdx.x;
  int lane = tid & 63, wid = tid >> 6;
  int wr = (wid >> 1) * 64, wc = (wid & 1) * 64;
  int r = lane & 15, g = lane >> 4;
  int m0 = blockIdx.x * 128, n0 = blockIdx.y * 128;

  f32x4 acc[4][4];
#pragma unroll
  for (int i = 0; i < 4; ++i)
#pragma unroll
    for (int j = 0; j < 4; ++j) acc[i][j] = (f32x4){0.f, 0.f, 0.f, 0.f};

  if (THREE) {
    const int NT = DMODEL / 32;
    stage32(Ah, DMODEL, m0, 0, st + 0 * 4096, tid);
    stage32(Al, DMODEL, m0, 0, st + 1 * 4096, tid);
    stage32(Bh, DMODEL, n0, 0, st + 2 * 4096, tid);
    stage32(Bl, DMODEL, n0, 0, st + 3 * 4096, tid);
    VMCNT0(); BAR();
    int cur = 0;
    for (int t = 0; t < NT; ++t) {
      if (t + 1 < NT) {
        int k0 = (t + 1) * 32;
        u16* nb = st + (cur ^ 1) * 16384;
        stage32(Ah, DMODEL, m0, k0, nb + 0 * 4096, tid);
        stage32(Al, DMODEL, m0, k0, nb + 1 * 4096, tid);
        stage32(Bh, DMODEL, n0, k0, nb + 2 * 4096, tid);
        stage32(Bl, DMODEL, n0, k0, nb + 3 * 4096, tid);
      }
      const u16* cb = st + cur * 16384;
      bf16x8 fa[4], fb[4], fal[4], fbl[4];
#pragma unroll
      for (int i = 0; i < 4; ++i) {
        fa[i]  = frag32(cb + 0 * 4096, wr + i * 16 + r, g);
        fal[i] = frag32(cb + 1 * 4096, wr + i * 16 + r, g);
        fb[i]  = frag32(cb + 2 * 4096, wc + i * 16 + r, g);
        fbl[i] = frag32(cb + 3 * 4096, wc + i * 16 + r, g);
      }
      __builtin_amdgcn_s_setprio(1);
#pragma unroll
      for (int i = 0; i < 4; ++i)
#pragma unroll
        for (int j = 0; j < 4; ++j) {
          MFMA16(acc[i][j], fa[i], fb[j]);
          MFMA16(acc[i][j], fa[i], fbl[j]);
          MFMA16(acc[i][j], fal[i], fb[j]);
        }
      __builtin_amdgcn_s_setprio(0);
      VMCNT0(); BAR();
      cur ^= 1;
    }
  } else {
    const int NT = DMODEL / 64;
    stage64(Ah, DMODEL, m0, 0, st + 0 * 8192, tid);
    stage64(Bh, DMODEL, n0, 0, st + 1 * 8192, tid);
    VMCNT0(); BAR();
    int cur = 0;
    for (int t = 0; t < NT; ++t) {
      if (t + 1 < NT) {
        int k0 = (t + 1) * 64;
        u16* nb = st + (cur ^ 1) * 16384;
        stage64(Ah, DMODEL, m0, k0, nb + 0 * 8192, tid);
        stage64(Bh, DMODEL, n0, k0, nb + 1 * 8192, tid);
      }
      const u16* cb = st + cur * 16384;
      __builtin_amdgcn_s_setprio(1);
#pragma unroll
      for (int ks = 0; ks < 2; ++ks) {
        bf16x8 fa[4], fb[4];
#pragma unroll
        for (int i = 0; i < 4; ++i) {
          fa[i] = frag64(cb + 0 * 8192, wr + i * 16 + r, ks * 4 + g);
          fb[i] = frag64(cb + 1 * 8192, wc + i * 16 + r, ks * 4 + g);
        }
#pragma unroll
        for (int i = 0; i < 4; ++i)
#pragma unroll
          for (int j = 0; j < 4; ++j) MFMA16(acc[i][j], fa[i], fb[j]);
      }
      __builtin_amdgcn_s_setprio(0);
      VMCNT0(); BAR();
      cur ^= 1;
    }
  }

#pragma unroll
  for (int i = 0; i < 4; ++i)
#pragma unroll
    for (int j = 0; j < 4; ++j) {
      int col = n0 + wc + j * 16 + r;
      float bv = bias[col];
#pragma unroll
      for (int t = 0; t < 4; ++t) {
        int row = m0 + wr + i * 16 + g * 4 + t;
        float v = (acc[i][j][t] + bv) * scale;
        if (SPLITOUT) {
          u16 hi = f2bf(v);
          outh[(size_t)row * DMODEL + col] = hi;
          outl[(size_t)row * DMODEL + col] = f2bf(v - bf2f(hi));
        } else {
          outT[(size_t)col * SEQLEN + row] = f2bf(v);  // transposed V
        }
      }
    }
}

// ---------------- scores: 2-phase pipeline + in-register softmax -----------
__global__ __launch_bounds__(256, 2) void scores_kernel(
    const u16* __restrict__ qh, const u16* __restrict__ ql,
    const u16* __restrict__ kh, const u16* __restrict__ kl,
    u16* __restrict__ P, float* __restrict__ mloc, float* __restrict__ tsum) {
  __shared__ __align__(16) u16 st[32768];  // 64KB staging; P-tile after loop
  __shared__ float sm_max[256];            // [2][128]
  __shared__ float sm_sum[256];

  int tid = threadIdx.x;
  int lane = tid & 63, wid = tid >> 6;
  int wr = (wid >> 1) * 64, wc = (wid & 1) * 64;
  int r = lane & 15, g = lane >> 4;
  int halfid = wid & 1;
  int m0 = blockIdx.x * 128, n0 = blockIdx.y * 128;

  f32x4 acc[4][4];
#pragma unroll
  for (int i = 0; i < 4; ++i)
#pragma unroll
    for (int j = 0; j < 4; ++j) acc[i][j] = (f32x4){0.f, 0.f, 0.f, 0.f};

  const int NT = DMODEL / 32;
  stage32(qh, DMODEL, m0, 0, st + 0 * 4096, tid);
  stage32(ql, DMODEL, m0, 0, st + 1 * 4096, tid);
  stage32(kh, DMODEL, n0, 0, st + 2 * 4096, tid);
  stage32(kl, DMODEL, n0, 0, st + 3 * 4096, tid);
  VMCNT0(); BAR();
  int cur = 0;
  for (int t = 0; t < NT; ++t) {
    if (t + 1 < NT) {
      int k0 = (t + 1) * 32;
      u16* nb = st + (cur ^ 1) * 16384;
      stage32(qh, DMODEL, m0, k0, nb + 0 * 4096, tid);
      stage32(ql, DMODEL, m0, k0, nb + 1 * 4096, tid);
      stage32(kh, DMODEL, n0, k0, nb + 2 * 4096, tid);
      stage32(kl, DMODEL, n0, k0, nb + 3 * 4096, tid);
    }
    const u16* cb = st + cur * 16384;
    bf16x8 fa[4], fb[4], fal[4], fbl[4];
#pragma unroll
    for (int i = 0; i < 4; ++i) {
      fa[i]  = frag32(cb + 0 * 4096, wr + i * 16 + r, g);
      fal[i] = frag32(cb + 1 * 4096, wr + i * 16 + r, g);
      fb[i]  = frag32(cb + 2 * 4096, wc + i * 16 + r, g);
      fbl[i] = frag32(cb + 3 * 4096, wc + i * 16 + r, g);
    }
    __builtin_amdgcn_s_setprio(1);
#pragma unroll
    for (int i = 0; i < 4; ++i)
#pragma unroll
      for (int j = 0; j < 4; ++j) {
        MFMA16(acc[i][j], fa[i], fb[j]);
        MFMA16(acc[i][j], fa[i], fbl[j]);
        MFMA16(acc[i][j], fal[i], fb[j]);
      }
    __builtin_amdgcn_s_setprio(0);
    VMCNT0(); BAR();
    cur ^= 1;
  }

  __syncthreads();  // staging done; st becomes the bf16 P-tile

  // per-row max over this wave's 64 cols, exchanged via sm_max
#pragma unroll
  for (int i = 0; i < 4; ++i)
#pragma unroll
    for (int t = 0; t < 4; ++t) {
      float m = fmaxf(fmaxf(acc[i][0][t], acc[i][1][t]),
                      fmaxf(acc[i][2][t], acc[i][3][t]));
      m = fmaxf(m, __shfl_xor(m, 1));
      m = fmaxf(m, __shfl_xor(m, 2));
      m = fmaxf(m, __shfl_xor(m, 4));
      m = fmaxf(m, __shfl_xor(m, 8));
      if (r == 0) sm_max[halfid * 128 + wr + i * 16 + g * 4 + t] = m;
    }
  __syncthreads();

  // exponentiate, write bf16 P-tile into LDS (XOR-swizzled), row sums
#pragma unroll
  for (int i = 0; i < 4; ++i)
#pragma unroll
    for (int t = 0; t < 4; ++t) {
      int R = wr + i * 16 + g * 4 + t;
      float mx = fmaxf(sm_max[R], sm_max[128 + R]);
      int sw = ((R >> 2) & 3) << 5;  // XOR bits 5-6 of col, varies per g
      float lsum = 0.f;
#pragma unroll
      for (int j = 0; j < 4; ++j) {
        float e = exp2f((acc[i][j][t] - mx) * 1.4426950408889634f);
        lsum += e;
        st[R * 128 + ((wc + j * 16 + r) ^ sw)] = f2bf(e);
      }
      lsum += __shfl_xor(lsum, 1);
      lsum += __shfl_xor(lsum, 2);
      lsum += __shfl_xor(lsum, 4);
      lsum += __shfl_xor(lsum, 8);
      if (r == 0) sm_sum[halfid * 128 + R] = lsum;
    }
  __syncthreads();

  // coalesced P write: 2048 16B-chunks, undoing the swizzle
#pragma unroll
  for (int k = 0; k < 8; ++k) {
    int cidx = k * 256 + tid;       // 0..2047
    int rrow = cidx >> 4;           // 16 chunks per row
    int col0 = (cidx & 15) * 8;
    int sw = ((rrow >> 2) & 3) << 5;
    u16x8 v = *(const u16x8*)(st + rrow * 128 + (col0 ^ sw));
    *(u16x8*)(P + (size_t)(m0 + rrow) * SEQLEN + n0 + col0) = v;
  }

  if (halfid == 0 && r == 0) {
#pragma unroll
    for (int i = 0; i < 4; ++i)
#pragma unroll
      for (int t = 0; t < 4; ++t) {
        int R = wr + i * 16 + g * 4 + t;
        int grow = m0 + R;
        mloc[(size_t)blockIdx.y * SEQLEN + grow] =
            fmaxf(sm_max[R], sm_max[128 + R]);
        tsum[(size_t)blockIdx.y * SEQLEN + grow] = sm_sum[R] + sm_sum[128 + R];
      }
  }
}

// ---------------- softmax finalize ----------------
__global__ void finalize_kernel(const float* __restrict__ mloc,
                                const float* __restrict__ tsum,
                                float* __restrict__ rowscale) {
  int rr = blockIdx.x * 256 + threadIdx.x;
  if (rr >= SEQLEN) return;
  float M = -3.0e38f;
#pragma unroll
  for (int t = 0; t < 32; ++t) M = fmaxf(M, mloc[t * SEQLEN + rr]);
  float l = 0.f;
#pragma unroll
  for (int t = 0; t < 32; ++t)
    l += tsum[t * SEQLEN + rr] * exp2f((mloc[t * SEQLEN + rr] - M) * 1.4426950408889634f);
  float inv = 1.0f / l;
#pragma unroll
  for (int t = 0; t < 32; ++t)
    rowscale[t * SEQLEN + rr] = exp2f((mloc[t * SEQLEN + rr] - M) * 1.4426950408889634f) * inv;
}

// ---------------- PV GEMM (2-phase pipeline, fused rescale) ----------------
// out[m][n] = sum_c rowscale[c][m] * (P'_c @ V_c)[m][n]; rescale applied to
// the bf16 A-fragment before MFMA (each fa[i] holds one P-row slice).
__global__ __launch_bounds__(256, 2) void pv_kernel(
    const u16* __restrict__ P, const u16* __restrict__ vT,
    const float* __restrict__ rowscale, float* __restrict__ out) {
  __shared__ __align__(16) u16 st[32768];  // 64 KB: 2 buffers
  int tid = threadIdx.x;
  int lane = tid & 63, wid = tid >> 6;
  int wr = (wid >> 1) * 64, wc = (wid & 1) * 64;
  int r = lane & 15, g = lane >> 4;
  int m0 = blockIdx.x * 128, n0 = blockIdx.y * 128;

  f32x4 acc[4][4];
#pragma unroll
  for (int i = 0; i < 4; ++i)
#pragma unroll
    for (int j = 0; j < 4; ++j) acc[i][j] = (f32x4){0.f, 0.f, 0.f, 0.f};

  const int NT = SEQLEN / 64;
  stage64(P, SEQLEN, m0, 0, st + 0 * 8192, tid);
  stage64(vT, SEQLEN, n0, 0, st + 1 * 8192, tid);
  VMCNT0(); BAR();
  int cur = 0;
  float rs[4];
  for (int t = 0; t < NT; ++t) {
    // rowscale load BEFORE stage issue so its wait doesn't drain the pipeline
    if ((t & 1) == 0) {
      int c = t >> 1;
#pragma unroll
      for (int i = 0; i < 4; ++i)
        rs[i] = rowscale[(size_t)c * SEQLEN + m0 + wr + i * 16 + r];
    }
    if (t + 1 < NT) {
      int k0 = (t + 1) * 64;
      u16* nb = st + (cur ^ 1) * 16384;
      stage64(P, SEQLEN, m0, k0, nb + 0 * 8192, tid);
      stage64(vT, SEQLEN, n0, k0, nb + 1 * 8192, tid);
    }
    const u16* cb = st + cur * 16384;
#pragma unroll
    for (int ks = 0; ks < 2; ++ks) {
      bf16x8 fa[4], fb[4];
#pragma unroll
      for (int i = 0; i < 4; ++i) {
        fa[i] = scale8(frag64(cb + 0 * 8192, wr + i * 16 + r, ks * 4 + g), rs[i]);
        fb[i] = frag64(cb + 1 * 8192, wc + i * 16 + r, ks * 4 + g);
      }
      __builtin_amdgcn_s_setprio(1);
#pragma unroll
      for (int i = 0; i < 4; ++i)
#pragma unroll
        for (int j = 0; j < 4; ++j) MFMA16(acc[i][j], fa[i], fb[j]);
      __builtin_amdgcn_s_setprio(0);
    }
    VMCNT0(); BAR();
    cur ^= 1;
  }
#pragma unroll
  for (int i = 0; i < 4; ++i)
#pragma unroll
    for (int j = 0; j < 4; ++j)
#pragma unroll
      for (int t = 0; t < 4; ++t)
        out[(size_t)(m0 + wr + i * 16 + g * 4 + t) * DMODEL + n0 + wc + j * 16 + r] =
            acc[i][j][t];
}

// ---------------- launch ----------------
extern "C" void kernel_launch(void* const* d_in, const int* in_sizes, int n_in,
                              void* d_out, int out_size, void* d_ws, size_t ws_size,
                              hipStream_t stream) {
  (void)in_sizes; (void)n_in; (void)out_size; (void)ws_size;
  const float* x  = (const float*)d_in[0];
  const float* WQ = (const float*)d_in[1];
  const float* WK = (const float*)d_in[2];
  const float* WV = (const float*)d_in[3];
  const float* bQ = (const float*)d_in[4];
  const float* bK = (const float*)d_in[5];
  const float* bV = (const float*)d_in[6];
  float* out = (float*)d_out;
  char* ws = (char*)d_ws;
  const size_t MB = 1ull << 20;

  // Prep region [0,28MB) is dead after projections; P (32MB) overlays it.
  u16* xh   = (u16*)(ws + 0);
  u16* xl   = (u16*)(ws + 8 * MB);
  u16* wqh  = (u16*)(ws + 16 * MB);
  u16* wql  = (u16*)(ws + 18 * MB);
  u16* wkh  = (u16*)(ws + 20 * MB);
  u16* wkl  = (u16*)(ws + 22 * MB);
  u16* wvh  = (u16*)(ws + 24 * MB);
  u16* wvl  = (u16*)(ws + 26 * MB);
  u16* P    = (u16*)(ws + 0);  // 32MB, written after prep region is dead
  u16* qh   = (u16*)(ws + 32 * MB);
  u16* ql   = (u16*)(ws + 40 * MB);
  u16* kh   = (u16*)(ws + 48 * MB);
  u16* kl   = (u16*)(ws + 56 * MB);
  u16* vT   = (u16*)(ws + 64 * MB);
  float* mloc     = (float*)(ws + 72 * MB);
  float* tsum     = (float*)(ws + 72 * MB + 512 * 1024);
  float* rowscale = (float*)(ws + 73 * MB);

  prep_kernel<<<2816, 256, 0, stream>>>(x, WQ, WK, WV, xh, xl, wqh, wql,
                                        wkh, wkl, wvh, wvl);

  dim3 gproj(32, 8);
  proj_kernel<true, true><<<gproj, 256, 0, stream>>>(xh, xl, wqh, wql, bQ,
                                                     1.0f / 32.0f, qh, ql, nullptr);
  proj_kernel<true, true><<<gproj, 256, 0, stream>>>(xh, xl, wkh, wkl, bK,
                                                     1.0f, kh, kl, nullptr);
  proj_kernel<false, false><<<gproj, 256, 0, stream>>>(xh, nullptr, wvh, nullptr, bV,
                                                       1.0f, nullptr, nullptr, vT);

  dim3 gsc(32, 32);
  scores_kernel<<<gsc, 256, 0, stream>>>(qh, ql, kh, kl, P, mloc, tsum);
  finalize_kernel<<<16, 256, 0, stream>>>(mloc, tsum, rowscale);

  dim3 gpv(32, 8);
  pv_kernel<<<gpv, 256, 0, stream>>>(P, vT, rowscale, out);
}

// Round 8
// 303.107 us; speedup vs baseline: 1.5908x; 1.1865x over previous
//
#include <hip/hip_runtime.h>
#include <hip/hip_bf16.h>
#include <stdint.h>

#define SEQLEN 4096
#define DMODEL 1024

typedef uint16_t u16;
typedef uint32_t u32;

typedef __bf16 bf16x8 __attribute__((ext_vector_type(8)));
typedef float  f32x4  __attribute__((ext_vector_type(4)));
typedef u16    u16x8  __attribute__((ext_vector_type(8)));
typedef u16    u16x4  __attribute__((ext_vector_type(4)));

// ---------------- helpers ----------------
__device__ __forceinline__ u16 f2bf(float f) {
  union { float f; u32 u; } a; a.f = f;
  return (u16)((a.u + 0x7FFFu + ((a.u >> 16) & 1u)) >> 16);  // RNE
}
__device__ __forceinline__ float bf2f(u16 h) {
  union { u32 u; float f; } a; a.u = ((u32)h) << 16;
  return a.f;
}

__device__ __forceinline__ void gl_lds16(const u16* g, u16* l) {
  __builtin_amdgcn_global_load_lds(
      (const __attribute__((address_space(1))) void*)g,
      (__attribute__((address_space(3))) void*)l,
      16, 0, 0);
}

// ---- staging: LDS dest linear (global_load_lds requirement); XOR swizzle
// applied on the per-lane GLOBAL source chunk (rule #21), undone at read.
__device__ __forceinline__ void stage64(const u16* __restrict__ g, int ld,
                                        int row0, int k0, u16* lds, int tid) {
#pragma unroll
  for (int it = 0; it < 4; ++it) {
    int u = tid + 256 * it;        // 16B-chunk index 0..1023
    int row = u >> 3;
    int cg = (u & 7) ^ (row & 7);
    gl_lds16(g + (size_t)(row0 + row) * ld + (size_t)(k0 + cg * 8), lds + u * 8);
  }
}
__device__ __forceinline__ bf16x8 frag64(const u16* lds, int row, int chunk) {
  return *(const bf16x8*)(lds + row * 64 + ((chunk ^ (row & 7)) << 3));
}

#define MFMA16(c, a, b) c = __builtin_amdgcn_mfma_f32_16x16x32_bf16(a, b, c, 0, 0, 0)

// ---------------- fused prep: 3x W-transpose+split, x split ----------------
__global__ void prep_kernel(const float* __restrict__ x,
                            const float* __restrict__ WQ,
                            const float* __restrict__ WK,
                            const float* __restrict__ WV,
                            u16* __restrict__ xh, u16* __restrict__ xl,
                            u16* __restrict__ wqh, u16* __restrict__ wql,
                            u16* __restrict__ wkh, u16* __restrict__ wkl,
                            u16* __restrict__ wvh, u16* __restrict__ wvl) {
  __shared__ float tile[64][65];
  int bx = blockIdx.x;
  if (bx < 768) {
    const float* W = (bx < 256) ? WQ : (bx < 512) ? WK : WV;
    u16* wth = (bx < 256) ? wqh : (bx < 512) ? wkh : wvh;
    u16* wtl = (bx < 256) ? wql : (bx < 512) ? wkl : wvl;
    int b = bx & 255;
    int n0 = (b & 15) * 64;
    int k0 = (b >> 4) * 64;
    int c = threadIdx.x & 63, r0 = threadIdx.x >> 6;
#pragma unroll
    for (int rr = 0; rr < 16; ++rr) {
      int r = r0 * 16 + rr;
      tile[r][c] = W[(size_t)(k0 + r) * DMODEL + n0 + c];
    }
    __syncthreads();
#pragma unroll
    for (int rr = 0; rr < 16; ++rr) {
      int n = r0 * 16 + rr;
      float f = tile[c][n];
      u16 hi = f2bf(f);
      wth[(size_t)(n0 + n) * DMODEL + k0 + c] = hi;
      wtl[(size_t)(n0 + n) * DMODEL + k0 + c] = f2bf(f - bf2f(hi));
    }
  } else {
    const int total = SEQLEN * DMODEL / 4;
    for (int idx = (bx - 768) * 256 + threadIdx.x; idx < total;
         idx += (gridDim.x - 768) * 256) {
      float4 f = ((const float4*)x)[idx];
      float ff[4] = {f.x, f.y, f.z, f.w};
      union { u16x4 v; u16 s[4]; } h, l;
#pragma unroll
      for (int uu = 0; uu < 4; ++uu) {
        u16 hi = f2bf(ff[uu]);
        h.s[uu] = hi;
        l.s[uu] = f2bf(ff[uu] - bf2f(hi));
      }
      ((u16x4*)xh)[idx] = h.v;
      ((u16x4*)xl)[idx] = l.v;
    }
  }
}

// ---------------- merged QKV projection GEMM ----------------
// grid (32, 8, 3): z=0 -> Q (3-term, scale 1/32, split out), z=1 -> K
// (3-term, split out), z=2 -> V (1-term, transposed bf16 out).
// R1-proven loop: BK=64, single-buffered 64KB LDS, syncthreads drain.
__global__ __launch_bounds__(256, 2) void qkv_kernel(
    const u16* __restrict__ xh, const u16* __restrict__ xl,
    const u16* __restrict__ wqh, const u16* __restrict__ wql,
    const u16* __restrict__ wkh, const u16* __restrict__ wkl,
    const u16* __restrict__ wvh, const u16* __restrict__ wvl,
    const float* __restrict__ bQ, const float* __restrict__ bK,
    const float* __restrict__ bV,
    u16* __restrict__ qh, u16* __restrict__ ql,
    u16* __restrict__ kh, u16* __restrict__ kl, u16* __restrict__ vT) {
  __shared__ __align__(16) u16 st[32768];  // 64 KB

  int tid = threadIdx.x;
  int lane = tid & 63, wid = tid >> 6;
  int wr = (wid >> 1) * 64, wc = (wid & 1) * 64;
  int r = lane & 15, g = lane >> 4;
  int m0 = blockIdx.x * 128, n0 = blockIdx.y * 128;
  int z = blockIdx.z;

  const u16* Bh = (z == 0) ? wqh : (z == 1) ? wkh : wvh;
  const u16* Bl = (z == 0) ? wql : wkl;
  const float* bias = (z == 0) ? bQ : (z == 1) ? bK : bV;
  float scale = (z == 0) ? (1.0f / 32.0f) : 1.0f;

  f32x4 acc[4][4];
#pragma unroll
  for (int i = 0; i < 4; ++i)
#pragma unroll
    for (int j = 0; j < 4; ++j) acc[i][j] = (f32x4){0.f, 0.f, 0.f, 0.f};

  if (z < 2) {
    for (int t = 0; t < DMODEL / 64; ++t) {
      int k0 = t * 64;
      __syncthreads();
      stage64(xh, DMODEL, m0, k0, st + 0 * 8192, tid);
      stage64(xl, DMODEL, m0, k0, st + 1 * 8192, tid);
      stage64(Bh, DMODEL, n0, k0, st + 2 * 8192, tid);
      stage64(Bl, DMODEL, n0, k0, st + 3 * 8192, tid);
      __syncthreads();
#pragma unroll
      for (int ks = 0; ks < 2; ++ks) {
        bf16x8 fa[4], fb[4], fal[4], fbl[4];
#pragma unroll
        for (int i = 0; i < 4; ++i) {
          fa[i]  = frag64(st + 0 * 8192, wr + i * 16 + r, ks * 4 + g);
          fal[i] = frag64(st + 1 * 8192, wr + i * 16 + r, ks * 4 + g);
          fb[i]  = frag64(st + 2 * 8192, wc + i * 16 + r, ks * 4 + g);
          fbl[i] = frag64(st + 3 * 8192, wc + i * 16 + r, ks * 4 + g);
        }
#pragma unroll
        for (int i = 0; i < 4; ++i)
#pragma unroll
          for (int j = 0; j < 4; ++j) {
            MFMA16(acc[i][j], fa[i], fb[j]);
            MFMA16(acc[i][j], fa[i], fbl[j]);
            MFMA16(acc[i][j], fal[i], fb[j]);
          }
      }
    }
    u16* outh = (z == 0) ? qh : kh;
    u16* outl = (z == 0) ? ql : kl;
#pragma unroll
    for (int i = 0; i < 4; ++i)
#pragma unroll
      for (int j = 0; j < 4; ++j) {
        int col = n0 + wc + j * 16 + r;
        float bv = bias[col];
#pragma unroll
        for (int t = 0; t < 4; ++t) {
          int row = m0 + wr + i * 16 + g * 4 + t;
          float v = (acc[i][j][t] + bv) * scale;
          u16 hi = f2bf(v);
          outh[(size_t)row * DMODEL + col] = hi;
          outl[(size_t)row * DMODEL + col] = f2bf(v - bf2f(hi));
        }
      }
  } else {
    for (int t = 0; t < DMODEL / 64; ++t) {
      int k0 = t * 64;
      __syncthreads();
      stage64(xh, DMODEL, m0, k0, st + 0 * 8192, tid);
      stage64(Bh, DMODEL, n0, k0, st + 1 * 8192, tid);
      __syncthreads();
#pragma unroll
      for (int ks = 0; ks < 2; ++ks) {
        bf16x8 fa[4], fb[4];
#pragma unroll
        for (int i = 0; i < 4; ++i) {
          fa[i] = frag64(st + 0 * 8192, wr + i * 16 + r, ks * 4 + g);
          fb[i] = frag64(st + 1 * 8192, wc + i * 16 + r, ks * 4 + g);
        }
#pragma unroll
        for (int i = 0; i < 4; ++i)
#pragma unroll
          for (int j = 0; j < 4; ++j) MFMA16(acc[i][j], fa[i], fb[j]);
      }
    }
#pragma unroll
    for (int i = 0; i < 4; ++i)
#pragma unroll
      for (int j = 0; j < 4; ++j) {
        int col = n0 + wc + j * 16 + r;
        float bv = bias[col];
#pragma unroll
        for (int t = 0; t < 4; ++t) {
          int row = m0 + wr + i * 16 + g * 4 + t;
          vT[(size_t)col * SEQLEN + row] = f2bf(acc[i][j][t] + bv);
        }
      }
  }
}

// ---------------- scores: R1 loop + in-register softmax epilogue -----------
__global__ __launch_bounds__(256, 2) void scores_kernel(
    const u16* __restrict__ qh, const u16* __restrict__ ql,
    const u16* __restrict__ kh, const u16* __restrict__ kl,
    u16* __restrict__ P, float* __restrict__ mloc, float* __restrict__ tsum) {
  __shared__ __align__(16) u16 st[32768];  // 64 KB staging; P-tile after loop
  __shared__ float sm_max[256];            // [2][128]
  __shared__ float sm_sum[256];

  int tid = threadIdx.x;
  int lane = tid & 63, wid = tid >> 6;
  int wr = (wid >> 1) * 64, wc = (wid & 1) * 64;
  int r = lane & 15, g = lane >> 4;
  int halfid = wid & 1;
  int m0 = blockIdx.x * 128, n0 = blockIdx.y * 128;

  f32x4 acc[4][4];
#pragma unroll
  for (int i = 0; i < 4; ++i)
#pragma unroll
    for (int j = 0; j < 4; ++j) acc[i][j] = (f32x4){0.f, 0.f, 0.f, 0.f};

  for (int t = 0; t < DMODEL / 64; ++t) {
    int k0 = t * 64;
    __syncthreads();
    stage64(qh, DMODEL, m0, k0, st + 0 * 8192, tid);
    stage64(ql, DMODEL, m0, k0, st + 1 * 8192, tid);
    stage64(kh, DMODEL, n0, k0, st + 2 * 8192, tid);
    stage64(kl, DMODEL, n0, k0, st + 3 * 8192, tid);
    __syncthreads();
#pragma unroll
    for (int ks = 0; ks < 2; ++ks) {
      bf16x8 fa[4], fb[4], fal[4], fbl[4];
#pragma unroll
      for (int i = 0; i < 4; ++i) {
        fa[i]  = frag64(st + 0 * 8192, wr + i * 16 + r, ks * 4 + g);
        fal[i] = frag64(st + 1 * 8192, wr + i * 16 + r, ks * 4 + g);
        fb[i]  = frag64(st + 2 * 8192, wc + i * 16 + r, ks * 4 + g);
        fbl[i] = frag64(st + 3 * 8192, wc + i * 16 + r, ks * 4 + g);
      }
#pragma unroll
      for (int i = 0; i < 4; ++i)
#pragma unroll
        for (int j = 0; j < 4; ++j) {
          MFMA16(acc[i][j], fa[i], fb[j]);
          MFMA16(acc[i][j], fa[i], fbl[j]);
          MFMA16(acc[i][j], fal[i], fb[j]);
        }
    }
  }

  __syncthreads();  // staging reads done; st[0..16384) becomes bf16 P-tile

  // per-row max over this wave's 64 cols, exchanged via sm_max
#pragma unroll
  for (int i = 0; i < 4; ++i)
#pragma unroll
    for (int t = 0; t < 4; ++t) {
      float m = fmaxf(fmaxf(acc[i][0][t], acc[i][1][t]),
                      fmaxf(acc[i][2][t], acc[i][3][t]));
      m = fmaxf(m, __shfl_xor(m, 1));
      m = fmaxf(m, __shfl_xor(m, 2));
      m = fmaxf(m, __shfl_xor(m, 4));
      m = fmaxf(m, __shfl_xor(m, 8));
      if (r == 0) sm_max[halfid * 128 + wr + i * 16 + g * 4 + t] = m;
    }
  __syncthreads();

  // exponentiate, write bf16 P-tile into LDS (XOR-swizzled), row sums
#pragma unroll
  for (int i = 0; i < 4; ++i)
#pragma unroll
    for (int t = 0; t < 4; ++t) {
      int R = wr + i * 16 + g * 4 + t;
      float mx = fmaxf(sm_max[R], sm_max[128 + R]);
      int sw = ((R >> 2) & 3) << 5;  // XOR bits 5-6 of col, varies per g
      float lsum = 0.f;
#pragma unroll
      for (int j = 0; j < 4; ++j) {
        float e = exp2f((acc[i][j][t] - mx) * 1.4426950408889634f);
        lsum += e;
        st[R * 128 + ((wc + j * 16 + r) ^ sw)] = f2bf(e);
      }
      lsum += __shfl_xor(lsum, 1);
      lsum += __shfl_xor(lsum, 2);
      lsum += __shfl_xor(lsum, 4);
      lsum += __shfl_xor(lsum, 8);
      if (r == 0) sm_sum[halfid * 128 + R] = lsum;
    }
  __syncthreads();

  // coalesced P write: 2048 16B-chunks, undoing the swizzle
#pragma unroll
  for (int k = 0; k < 8; ++k) {
    int cidx = k * 256 + tid;       // 0..2047
    int rrow = cidx >> 4;           // 16 chunks per row
    int col0 = (cidx & 15) * 8;
    int sw = ((rrow >> 2) & 3) << 5;
    u16x8 v = *(const u16x8*)(st + rrow * 128 + (col0 ^ sw));
    *(u16x8*)(P + (size_t)(m0 + rrow) * SEQLEN + n0 + col0) = v;
  }

  if (halfid == 0 && r == 0) {
#pragma unroll
    for (int i = 0; i < 4; ++i)
#pragma unroll
      for (int t = 0; t < 4; ++t) {
        int R = wr + i * 16 + g * 4 + t;
        int grow = m0 + R;
        mloc[(size_t)blockIdx.y * SEQLEN + grow] =
            fmaxf(sm_max[R], sm_max[128 + R]);
        tsum[(size_t)blockIdx.y * SEQLEN + grow] = sm_sum[R] + sm_sum[128 + R];
      }
  }
}

// ---------------- softmax finalize ----------------
__global__ void finalize_kernel(const float* __restrict__ mloc,
                                const float* __restrict__ tsum,
                                float* __restrict__ rowscale) {
  int rr = blockIdx.x * 256 + threadIdx.x;
  if (rr >= SEQLEN) return;
  float M = -3.0e38f;
#pragma unroll
  for (int t = 0; t < 32; ++t) M = fmaxf(M, mloc[t * SEQLEN + rr]);
  float l = 0.f;
#pragma unroll
  for (int t = 0; t < 32; ++t)
    l += tsum[t * SEQLEN + rr] * exp2f((mloc[t * SEQLEN + rr] - M) * 1.4426950408889634f);
  float inv = 1.0f / l;
#pragma unroll
  for (int t = 0; t < 32; ++t)
    rowscale[t * SEQLEN + rr] = exp2f((mloc[t * SEQLEN + rr] - M) * 1.4426950408889634f) * inv;
}

// ---------------- PV GEMM with fp32 part-merge rescale ----------------
// out[m][n] = sum_c rowscale[c][m] * (P'_c @ V_c)[m][n]  (c = 128-kv chunks)
// part-merge in fp32 after each chunk; VGPR ~190 fits at launch_bounds(256,2).
__global__ __launch_bounds__(256, 2) void pv_kernel(
    const u16* __restrict__ P, const u16* __restrict__ vT,
    const float* __restrict__ rowscale, float* __restrict__ out) {
  __shared__ __align__(16) u16 st[16384];  // 32 KB single buffer
  int tid = threadIdx.x;
  int lane = tid & 63, wid = tid >> 6;
  int wr = (wid >> 1) * 64, wc = (wid & 1) * 64;
  int r = lane & 15, g = lane >> 4;
  int m0 = blockIdx.x * 128, n0 = blockIdx.y * 128;

  f32x4 acc[4][4], part[4][4];
#pragma unroll
  for (int i = 0; i < 4; ++i)
#pragma unroll
    for (int j = 0; j < 4; ++j) acc[i][j] = (f32x4){0.f, 0.f, 0.f, 0.f};

  for (int c = 0; c < SEQLEN / 128; ++c) {
    f32x4 rs[4];
#pragma unroll
    for (int i = 0; i < 4; ++i)
      rs[i] = *(const f32x4*)&rowscale[(size_t)c * SEQLEN + m0 + wr + i * 16 + g * 4];
#pragma unroll
    for (int i = 0; i < 4; ++i)
#pragma unroll
      for (int j = 0; j < 4; ++j) part[i][j] = (f32x4){0.f, 0.f, 0.f, 0.f};
#pragma unroll
    for (int s2 = 0; s2 < 2; ++s2) {
      int k0 = c * 128 + s2 * 64;
      __syncthreads();
      stage64(P, SEQLEN, m0, k0, st + 0 * 8192, tid);
      stage64(vT, SEQLEN, n0, k0, st + 1 * 8192, tid);
      __syncthreads();
#pragma unroll
      for (int ks = 0; ks < 2; ++ks) {
        bf16x8 fa[4], fb[4];
#pragma unroll
        for (int i = 0; i < 4; ++i) {
          fa[i] = frag64(st + 0 * 8192, wr + i * 16 + r, ks * 4 + g);
          fb[i] = frag64(st + 1 * 8192, wc + i * 16 + r, ks * 4 + g);
        }
#pragma unroll
        for (int i = 0; i < 4; ++i)
#pragma unroll
          for (int j = 0; j < 4; ++j) MFMA16(part[i][j], fa[i], fb[j]);
      }
    }
#pragma unroll
    for (int i = 0; i < 4; ++i)
#pragma unroll
      for (int j = 0; j < 4; ++j) acc[i][j] += part[i][j] * rs[i];
  }
#pragma unroll
  for (int i = 0; i < 4; ++i)
#pragma unroll
    for (int j = 0; j < 4; ++j)
#pragma unroll
      for (int t = 0; t < 4; ++t)
        out[(size_t)(m0 + wr + i * 16 + g * 4 + t) * DMODEL + n0 + wc + j * 16 + r] =
            acc[i][j][t];
}

// ---------------- launch ----------------
extern "C" void kernel_launch(void* const* d_in, const int* in_sizes, int n_in,
                              void* d_out, int out_size, void* d_ws, size_t ws_size,
                              hipStream_t stream) {
  (void)in_sizes; (void)n_in; (void)out_size; (void)ws_size;
  const float* x  = (const float*)d_in[0];
  const float* WQ = (const float*)d_in[1];
  const float* WK = (const float*)d_in[2];
  const float* WV = (const float*)d_in[3];
  const float* bQ = (const float*)d_in[4];
  const float* bK = (const float*)d_in[5];
  const float* bV = (const float*)d_in[6];
  float* out = (float*)d_out;
  char* ws = (char*)d_ws;
  const size_t MB = 1ull << 20;

  // Prep region [0,28MB) is dead after projections; P (32MB) overlays it.
  u16* xh   = (u16*)(ws + 0);
  u16* xl   = (u16*)(ws + 8 * MB);
  u16* wqh  = (u16*)(ws + 16 * MB);
  u16* wql  = (u16*)(ws + 18 * MB);
  u16* wkh  = (u16*)(ws + 20 * MB);
  u16* wkl  = (u16*)(ws + 22 * MB);
  u16* wvh  = (u16*)(ws + 24 * MB);
  u16* wvl  = (u16*)(ws + 26 * MB);
  u16* P    = (u16*)(ws + 0);  // 32MB, written after prep region is dead
  u16* qh   = (u16*)(ws + 32 * MB);
  u16* ql   = (u16*)(ws + 40 * MB);
  u16* kh   = (u16*)(ws + 48 * MB);
  u16* kl   = (u16*)(ws + 56 * MB);
  u16* vT   = (u16*)(ws + 64 * MB);
  float* mloc     = (float*)(ws + 72 * MB);
  float* tsum     = (float*)(ws + 72 * MB + 512 * 1024);
  float* rowscale = (float*)(ws + 73 * MB);

  prep_kernel<<<2816, 256, 0, stream>>>(x, WQ, WK, WV, xh, xl, wqh, wql,
                                        wkh, wkl, wvh, wvl);

  dim3 gqkv(32, 8, 3);
  qkv_kernel<<<gqkv, 256, 0, stream>>>(xh, xl, wqh, wql, wkh, wkl, wvh, wvl,
                                       bQ, bK, bV, qh, ql, kh, kl, vT);

  dim3 gsc(32, 32);
  scores_kernel<<<gsc, 256, 0, stream>>>(qh, ql, kh, kl, P, mloc, tsum);
  finalize_kernel<<<16, 256, 0, stream>>>(mloc, tsum, rowscale);

  dim3 gpv(32, 8);
  pv_kernel<<<gpv, 256, 0, stream>>>(P, vT, rowscale, out);
}